// Round 6
// baseline (464.688 us; speedup 1.0000x reference)
//
#include <hip/hip_runtime.h>
#include <math.h>

#define S_LEN  16384
#define NCONV  128
#define NBATCH 256
#define TPB    1024   // 16 waves; one conv per wave
#define ZSLOT  16384  // lds slot holding 0.0f; all OOB taps clamp here

typedef float __attribute__((address_space(1))) as1_float;
typedef float __attribute__((address_space(3))) as3_float;

__device__ __forceinline__ int geti(const int* __restrict__ a, int i, int is64) {
  return is64 ? a[2 * i] : a[i];
}

// wave-uniform value -> SGPR
__device__ __forceinline__ float sgpr_f(float v) {
  return __int_as_float(__builtin_amdgcn_readfirstlane(__float_as_int(v)));
}

// OOB-safe LDS read: pos<0 wraps huge unsigned -> clamps to ZSLOT (=0.0f)
__device__ __forceinline__ float lds_at(const float* sh, int pos) {
  unsigned idx = (unsigned)pos;
  idx = idx > (unsigned)ZSLOT ? (unsigned)ZSLOT : idx;
  return sh[idx];
}

// ---------- scalar rotate-walk (d==1, odd-d remainder class) ----------
template <int K, bool SAFE, bool EXACT>
__device__ __forceinline__ void walk(
    const float* sh, const float* w, float bval,
    int d, int p, int r, int q0, int q1, float& mx, int& cnt)
{
  const int n = q1 - q0;
  if (n <= 0) return;
  float win[K];
  int pos = r - p + q0 * d;
#pragma unroll
  for (int t = 0; t < K - 1; ++t) {
    win[t] = SAFE ? lds_at(sh, pos) : sh[pos];
    pos += d;
  }
  for (int i = 0; i < n; i += K) {
#pragma unroll
    for (int s = 0; s < K; ++s) {
      win[(s + K - 1) % K] = SAFE ? lds_at(sh, pos) : sh[pos];
      pos += d;
      float a = bval;
#pragma unroll
      for (int t = 0; t < K; ++t) a = fmaf(w[t], win[(s + t) % K], a);
      if (EXACT || (i + s < n)) { mx = fmaxf(mx, a); cnt += (a >= 0.f); }
    }
  }
}

template <int K>
__device__ __forceinline__ void cls(
    const float* sh, const float* w, float bval,
    int d, int p, int r, int q0, int q1, float& mx, int& cnt)
{
  if (q1 <= q0) return;
  const int qlo = (p > r) ? (p - r + d - 1) / d : 0;
  const int qhi = (S_LEN - 1 - r + p) / d - (K - 1);
  int i0 = min(max(qlo, q0), q1);
  int i1 = min(qhi + 1, q1);
  if (i1 < i0) i1 = i0;
  const int nc = (i1 - i0) / K;
  const int i1a = i0 + nc * K;
  walk<K, true, false>(sh, w, bval, d, p, r, q0, i0, mx, cnt);
  if (nc > 0) walk<K, false, true>(sh, w, bval, d, p, r, i0, i1a, mx, cnt);
  walk<K, true, false>(sh, w, bval, d, p, r, i1a, q1, mx, cnt);
}

// split class r's q-range over all 64 lanes (stagger for bank spread)
template <int K>
__device__ __forceinline__ void scalar_split(
    const float* sh, const float* w, float bval,
    int d, int p, int r, int L, int lane, float& mx, int& cnt)
{
  if (r >= L) return;
  const int Q  = (L - 1 - r) / d + 1;
  const int mm = Q >> 6;
  const int v  = lane;
  const int sA = (mm >= 32) ? (v & 31) : (((v & 31) * mm) >> 5);
  const int vB = v + 1;
  const int sB = (mm >= 32) ? (vB & 31) : (((vB & 31) * mm) >> 5);
  const int q0 = (int)(((long long)Q * v) >> 6) + sA;     // v==0 -> 0
  const int q1 = (v == 63) ? Q : (int)(((long long)Q * vB) >> 6) + sB;
  cls<K>(sh, w, bval, d, p, r, q0, q1, mx, cnt);
}

// ---------- pair walk: classes (2g, 2g+1) -> adjacent LDS addresses.
// One fused ds_read2_b32 per q feeds TWO outputs. ----------
template <int K, bool SAFE, bool EXACT>
__device__ __forceinline__ void pwalk(
    const float* sh, const float* w, float bval,
    int d, int p, int r0, int q0, int q1, float& mx, int& cnt)
{
  const int n = q1 - q0;
  if (n <= 0) return;
  float wl[K], wh[K];
  int pos = r0 - p + q0 * d;
#pragma unroll
  for (int t = 0; t < K - 1; ++t) {
    wl[t] = SAFE ? lds_at(sh, pos)     : sh[pos];
    wh[t] = SAFE ? lds_at(sh, pos + 1) : sh[pos + 1];
    pos += d;
  }
  for (int i = 0; i < n; i += K) {
#pragma unroll
    for (int s = 0; s < K; ++s) {
      wl[(s + K - 1) % K] = SAFE ? lds_at(sh, pos)     : sh[pos];
      wh[(s + K - 1) % K] = SAFE ? lds_at(sh, pos + 1) : sh[pos + 1];
      pos += d;
      float a0 = bval, a1 = bval;
#pragma unroll
      for (int t = 0; t < K; ++t) {
        a0 = fmaf(w[t], wl[(s + t) % K], a0);
        a1 = fmaf(w[t], wh[(s + t) % K], a1);
      }
      if (EXACT || (i + s < n)) {
        mx = fmaxf(mx, fmaxf(a0, a1));
        cnt += (a0 >= 0.f) + (a1 >= 0.f);
      }
    }
  }
}

template <int K>
__device__ __forceinline__ void pcls(
    const float* sh, const float* w, float bval,
    int d, int p, int g, int q0, int q1, float& mx, int& cnt)
{
  if (q1 <= q0) return;
  const int r0 = 2 * g, r1 = r0 + 1;
  const int qlo = (p > r0) ? (p - r0 + d - 1) / d : 0;     // class r0 is tighter low
  const int qhi = (S_LEN - 1 - r1 + p) / d - (K - 1);      // class r1 is tighter high
  int i0 = min(max(qlo, q0), q1);
  int i1 = min(qhi + 1, q1);
  if (i1 < i0) i1 = i0;
  const int nc = (i1 - i0) / K;
  const int i1a = i0 + nc * K;
  pwalk<K, true, false>(sh, w, bval, d, p, r0, q0, i0, mx, cnt);
  if (nc > 0) pwalk<K, false, true>(sh, w, bval, d, p, r0, i0, i1a, mx, cnt);
  pwalk<K, true, false>(sh, w, bval, d, p, r0, i1a, q1, mx, cnt);
}

// one dangling output (first class has one more q than second)
template <int K>
__device__ __forceinline__ void one_out(
    const float* sh, const float* w, float bval,
    int d, int p, int j, float& mx, int& cnt)
{
  float a = bval;
  int pos = j - p;
#pragma unroll
  for (int t = 0; t < K; ++t) { a = fmaf(w[t], lds_at(sh, pos), a); pos += d; }
  mx = fmaxf(mx, a);
  cnt += (a >= 0.f);
}

template <int K>
__device__ __forceinline__ void conv_wave(
    const float* sh, const float* w, float bval,
    int d, int p, int L, int lane, float& mx, int& cnt)
{
  if (d == 1) {
    scalar_split<K>(sh, w, bval, 1, p, 0, L, lane, mx, cnt);
    return;
  }
  const int npair = d >> 1;
  if (npair >= 64) {
    // whole pair-columns per lane
    for (int g = lane; g < npair; g += 64) {
      const int r0 = 2 * g;
      const int Q1 = (r0 <= L - 1) ? (L - 1 - r0) / d + 1 : 0;
      const int Q2 = (r0 + 1 <= L - 1) ? (L - 2 - r0) / d + 1 : 0;
      pcls<K>(sh, w, bval, d, p, g, 0, Q2, mx, cnt);
      if (Q1 > Q2) one_out<K>(sh, w, bval, d, p, r0 + (Q1 - 1) * d, mx, cnt);
    }
    if ((d & 1) && lane == 0) {  // remainder class: short (Q <= ~129)
      const int r = d - 1;
      if (r < L) cls<K>(sh, w, bval, d, p, r, 0, (L - 1 - r) / d + 1, mx, cnt);
    }
  } else {
    // split each pair-column's q-range among its lanes, staggered starts
    const int g  = lane % npair;
    const int v  = lane / npair;
    const int nv = (63 - g) / npair + 1;
    const int r0 = 2 * g;
    const int Q1 = (r0 <= L - 1) ? (L - 1 - r0) / d + 1 : 0;
    const int Q2 = (r0 + 1 <= L - 1) ? (L - 2 - r0) / d + 1 : 0;
    const int mm = Q2 / nv;
    const int sA = (mm >= 32) ? (v & 31) : (((v & 31) * mm) >> 5);
    const int vB = v + 1;
    const int sB = (mm >= 32) ? (vB & 31) : (((vB & 31) * mm) >> 5);
    const int q0 = (int)(((long long)Q2 * v) / nv) + sA;   // v==0 -> 0
    const int q1 = (v == nv - 1) ? Q2 : (int)(((long long)Q2 * vB) / nv) + sB;
    pcls<K>(sh, w, bval, d, p, g, q0, q1, mx, cnt);
    if (v == nv - 1 && Q1 > Q2)
      one_out<K>(sh, w, bval, d, p, r0 + (Q1 - 1) * d, mx, cnt);
    if (d & 1)  // remainder class over all lanes
      scalar_split<K>(sh, w, bval, d, p, d - 1, L, lane, mx, cnt);
  }
}

__global__ __launch_bounds__(TPB, 8) void rocket_feats(
    const float* __restrict__ x, const float* __restrict__ W,
    const float* __restrict__ bias,
    const int* __restrict__ ks, const int* __restrict__ dil,
    const int* __restrict__ pad, float* __restrict__ out)
{
  __shared__ float sh[S_LEN + 1];  // 64.5KB -> 2 blocks/CU, 32 waves/CU

  const int tid  = threadIdx.x;
  const int blk  = blockIdx.x;     // blk = g*256 + b  =>  XCD(blk%8) = b%8:
  const int g    = blk >> 8;       // all 8 conv-group blocks of a row land on
  const int b    = blk & 255;      // the SAME XCD -> row fetched once per XCD
  const int lane = tid & 63, wid = tid >> 6;

  const float* xrow = x + (size_t)b * S_LEN;

  {
    const float* gb = xrow + lane * 4;
#pragma unroll
    for (int c = 0; c < 4; ++c) {
      const int off = (wid * 4 + c) * 256;  // floats
      __builtin_amdgcn_global_load_lds((const as1_float*)(gb + off),
                                       (as3_float*)(sh + off), 16, 0, 0);
    }
  }
  if (tid == 0) sh[ZSLOT] = 0.f;
  __syncthreads();  // only barrier

  const int is64 = (ks[1] == 0);
  const int ci = g * 16 + wid;
  const int k = geti(ks, ci, is64);
  const int d = geti(dil, ci, is64);
  const int p = geti(pad, ci, is64);
  const int L = S_LEN + 2 * p - d * (k - 1);
  const float bval = sgpr_f(bias[ci]);

  float mx = -INFINITY;
  int cnt = 0;

  if (k == 7) {
    float w[7];
#pragma unroll
    for (int t = 0; t < 7; ++t) w[t] = sgpr_f(W[ci * 11 + t]);
    conv_wave<7>(sh, w, bval, d, p, L, lane, mx, cnt);
  } else if (k == 9) {
    float w[9];
#pragma unroll
    for (int t = 0; t < 9; ++t) w[t] = sgpr_f(W[ci * 11 + t]);
    conv_wave<9>(sh, w, bval, d, p, L, lane, mx, cnt);
  } else {
    float w[11];
#pragma unroll
    for (int t = 0; t < 11; ++t) w[t] = sgpr_f(W[ci * 11 + t]);
    conv_wave<11>(sh, w, bval, d, p, L, lane, mx, cnt);
  }

#pragma unroll
  for (int off = 32; off > 0; off >>= 1) {
    mx = fmaxf(mx, __shfl_down(mx, off, 64));
    cnt += __shfl_down(cnt, off, 64);
  }
  if (lane == 0) {
    out[(size_t)b * (2 * NCONV) + 2 * ci]     = mx;
    out[(size_t)b * (2 * NCONV) + 2 * ci + 1] = (float)cnt / (float)L;
  }
}

extern "C" void kernel_launch(void* const* d_in, const int* in_sizes, int n_in,
                              void* d_out, int out_size, void* d_ws, size_t ws_size,
                              hipStream_t stream) {
  const float* x    = (const float*)d_in[0];
  const float* W    = (const float*)d_in[1];
  const float* bias = (const float*)d_in[2];
  const int*   ks   = (const int*)d_in[3];
  const int*   dil  = (const int*)d_in[4];
  const int*   pad  = (const int*)d_in[5];
  float* out = (float*)d_out;

  hipLaunchKernelGGL(rocket_feats, dim3(NBATCH * 8), dim3(TPB), 0, stream,
                     x, W, bias, ks, dil, pad, out);
}

// Round 7
// 450.442 us; speedup vs baseline: 1.0316x; 1.0316x over previous
//
#include <hip/hip_runtime.h>
#include <math.h>

#define S_LEN   16384
#define NCONV   128
#define NBATCH  256
#define TPB     1024   // 16 waves; one conv per wave
#define ZSLOT   16384  // lds slot holding 0.0f; all OOB taps clamp here
#define DSTRIDE 20     // dwords per conv descriptor in ws
// desc: [0]=d [1]=p [2]=A(L/d) [3]=B(L%d) [4]=ci [5]=1/L [6]=bias [7..17]=w

typedef float __attribute__((address_space(1))) as1_float;
typedef float __attribute__((address_space(3))) as3_float;

// ---------------- setup kernel: descriptors + LPT balancing ----------------
__global__ void setup_desc(const int* __restrict__ ks, const int* __restrict__ dil,
                           const int* __restrict__ pad, const float* __restrict__ W,
                           const float* __restrict__ bias, int* __restrict__ ws)
{
  __shared__ int cost_s[NCONV];
  const int ci = threadIdx.x;  // blockDim == 128
  const int is64 = (ks[1] == 0);
  const int k = is64 ? ks[2 * ci]  : ks[ci];
  const int d = is64 ? dil[2 * ci] : dil[ci];
  const int p = is64 ? pad[2 * ci] : pad[ci];
  const int L = S_LEN + 2 * p - d * (k - 1);
  const int A = L / d, B = L - A * d;
  const int cost = 17 * L + 10 * d;  // outputs*ops + priming
  cost_s[ci] = cost;
  __syncthreads();
  // parallel rank (descending cost, ties by index)
  int rank = 0;
  for (int j = 0; j < NCONV; ++j) {
    const int cj = cost_s[j];
    rank += (cj > cost) || (cj == cost && j < ci);
  }
  // snake-deal ranks into 8 groups x 16 wave-levels -> balanced blocks
  const int lvl = rank >> 3;
  int gg = rank & 7;
  if (lvl & 1) gg = 7 - gg;
  const int slot = gg * 16 + lvl;
  int* dsc = ws + slot * DSTRIDE;
  dsc[0] = d; dsc[1] = p; dsc[2] = A; dsc[3] = B; dsc[4] = ci;
  ((float*)dsc)[5] = 1.0f / (float)L;
  ((float*)dsc)[6] = bias[ci];
#pragma unroll
  for (int t = 0; t < 11; ++t) ((float*)dsc)[7 + t] = W[ci * 11 + t];
}

// ---------------- hot kernel helpers ----------------
__device__ __forceinline__ float sgpr_f(float v) {
  return __int_as_float(__builtin_amdgcn_readfirstlane(__float_as_int(v)));
}
__device__ __forceinline__ int sgpr_i(int v) {
  return __builtin_amdgcn_readfirstlane(v);
}
// OOB-safe LDS read: pos<0 wraps huge unsigned -> clamps to ZSLOT (=0.0f)
__device__ __forceinline__ float lds_at(const float* sh, int pos) {
  unsigned idx = (unsigned)pos;
  idx = idx > (unsigned)ZSLOT ? (unsigned)ZSLOT : idx;
  return sh[idx];
}

// K=11 rotate walk, clamped loads everywhere. EXACT: n % 11 == 0, guard-free.
template <bool EXACT>
__device__ __forceinline__ void walk11(
    const float* sh, const float* w, float bval,
    int d, int sb, int q0, int q1, float& mx, int& cnt)
{
  const int n = q1 - q0;
  if (n <= 0) return;
  float win[11];
  int pos = sb + q0 * d;
#pragma unroll
  for (int t = 0; t < 10; ++t) { win[t] = lds_at(sh, pos); pos += d; }
  for (int i = 0; i < n; i += 11) {
#pragma unroll
    for (int s = 0; s < 11; ++s) {
      win[(s + 10) % 11] = lds_at(sh, pos);
      pos += d;
      float a = bval;
#pragma unroll
      for (int t = 0; t < 11; ++t) a = fmaf(w[t], win[(s + t) % 11], a);
      if (EXACT || (i + s < n)) { mx = fmaxf(mx, a); cnt += (a >= 0.f); }
    }
  }
}

__device__ __forceinline__ void run_range(
    const float* sh, const float* w, float bval,
    int d, int sb, int q0, int q1, float& mx, int& cnt)
{
  const int n = q1 - q0;
  if (n <= 0) return;
  const int n11 = n - n % 11;  // const modulo -> magic mul
  walk11<true >(sh, w, bval, d, sb, q0, q0 + n11, mx, cnt);
  walk11<false>(sh, w, bval, d, sb, q0 + n11, q1, mx, cnt);
}

__device__ __forceinline__ float rcpf(float x) { return __builtin_amdgcn_rcpf(x); }

// ---------------- hot kernel ----------------
__global__ __launch_bounds__(TPB, 8) void rocket_feats(
    const float* __restrict__ x, const int* __restrict__ ws,
    float* __restrict__ out)
{
  __shared__ float sh[S_LEN + 1];  // 64.5KB -> 2 blocks/CU, 32 waves/CU

  const int tid  = threadIdx.x;
  const int blk  = blockIdx.x;   // blk = b*8 + g: a row's 8 blocks are
  const int g    = blk & 7;      // dispatch-adjacent -> LLC absorbs re-reads
  const int b    = blk >> 3;
  const int lane = tid & 63, wid = tid >> 6;

  // stage row -> LDS (async, 16B wide)
  const float* xrow = x + (size_t)b * S_LEN;
  {
    const float* gb = xrow + lane * 4;
#pragma unroll
    for (int c = 0; c < 4; ++c) {
      const int off = (wid * 4 + c) * 256;  // floats
      __builtin_amdgcn_global_load_lds((const as1_float*)(gb + off),
                                       (as3_float*)(sh + off), 16, 0, 0);
    }
  }
  if (tid == 0) sh[ZSLOT] = 0.f;

  // wave-uniform descriptor -> SGPRs (overlaps with staging)
  const int* dsc = ws + (g * 16 + wid) * DSTRIDE;
  const int d  = sgpr_i(dsc[0]);
  const int p  = sgpr_i(dsc[1]);
  const int A  = sgpr_i(dsc[2]);
  const int B  = sgpr_i(dsc[3]);
  const int ci = sgpr_i(dsc[4]);
  const float invL = sgpr_f(((const float*)dsc)[5]);
  const float bval = sgpr_f(((const float*)dsc)[6]);
  float w[11];
#pragma unroll
  for (int t = 0; t < 11; ++t) w[t] = sgpr_f(((const float*)dsc)[7 + t]);

  __syncthreads();  // only barrier

  float mx = -INFINITY;
  int cnt = 0;

  if (d >= 64) {
    // lane walks whole classes r = lane, lane+64, ... (adjacent lanes ->
    // adjacent LDS addresses, conflict-free)
    for (int r = lane; r < d; r += 64) {
      const int Q = A + (r < B);
      run_range(sh, w, bval, d, r - p, 0, Q, mx, cnt);
    }
  } else {
    // lane -> (class r, sub-index v); division-free via v_rcp + fixup
    const float rd = rcpf((float)d);
    int v = (int)((float)lane * rd);
    int r = lane - v * d;
    if (r < 0)  { v -= 1; r += d; }
    if (r >= d) { v += 1; r -= d; }
    int nv = (int)((float)(63 - r) * rd) + 1;  // lanes on this class
    while ((nv - 1) * d > 63 - r) --nv;
    while (nv * d <= 63 - r) ++nv;
    const int Q = A + (r < B);
    // proportional split with mod-32 stagger (bank spread). Boundaries are
    // computed by identical float exprs in adjacent lanes -> exact tiling.
    const float rn = rcpf((float)nv);
    const int mm = (int)((float)Q * rn);
    const int sA = (mm >= 32) ? (v & 31) : (((v & 31) * mm) >> 5);
    const int vB = v + 1;
    const int sB = (mm >= 32) ? (vB & 31) : (((vB & 31) * mm) >> 5);
    int q0 = (int)((float)(Q * v) * rn) + sA;              // v==0 -> 0
    int q1 = (v == nv - 1) ? Q : (int)((float)(Q * vB) * rn) + sB;
    run_range(sh, w, bval, d, r - p, q0, q1, mx, cnt);
  }

  // per-wave shuffle reduction; no cross-wave reduce needed
#pragma unroll
  for (int off = 32; off > 0; off >>= 1) {
    mx = fmaxf(mx, __shfl_down(mx, off, 64));
    cnt += __shfl_down(cnt, off, 64);
  }
  if (lane == 0) {
    out[(size_t)b * (2 * NCONV) + 2 * ci]     = mx;
    out[(size_t)b * (2 * NCONV) + 2 * ci + 1] = (float)cnt * invL;
  }
}

extern "C" void kernel_launch(void* const* d_in, const int* in_sizes, int n_in,
                              void* d_out, int out_size, void* d_ws, size_t ws_size,
                              hipStream_t stream) {
  const float* x    = (const float*)d_in[0];
  const float* W    = (const float*)d_in[1];
  const float* bias = (const float*)d_in[2];
  const int*   ks   = (const int*)d_in[3];
  const int*   dil  = (const int*)d_in[4];
  const int*   pad  = (const int*)d_in[5];
  float* out = (float*)d_out;
  int*   ws  = (int*)d_ws;  // needs 128*20*4 = 10240 bytes

  hipLaunchKernelGGL(setup_desc, dim3(1), dim3(NCONV), 0, stream,
                     ks, dil, pad, W, bias, ws);
  hipLaunchKernelGGL(rocket_feats, dim3(NBATCH * 8), dim3(TPB), 0, stream,
                     x, ws, out);
}